// Round 5
// baseline (194.780 us; speedup 1.0000x reference)
//
#include <hip/hip_runtime.h>

typedef __attribute__((ext_vector_type(8))) short bf16x8;
typedef __attribute__((ext_vector_type(4))) float f32x4;

// fp32 -> bf16 (round-to-nearest-even), finite inputs only
__device__ __forceinline__ unsigned short f2b(float f) {
  union { float f; unsigned u; } v; v.f = f;
  return (unsigned short)((v.u + 0x7FFFu + ((v.u >> 16) & 1u)) >> 16);
}

// Fused fp32->bf16 cast for x, W_attn, W_proj (one launch)
#define XN4   786432   // 4096*768/4
#define WAN4  442368   // 2304*768/4
#define WPN4  147456   // 768*768/4
__global__ void cvt_all(const float* __restrict__ x, const float* __restrict__ Wa,
                        const float* __restrict__ Wp,
                        unsigned short* __restrict__ xb, unsigned short* __restrict__ Wab,
                        unsigned short* __restrict__ Wpb) {
  int i = blockIdx.x * 256 + threadIdx.x;
  const float* src; unsigned short* dst; int off;
  if (i < XN4)            { src = x;  dst = xb;  off = i; }
  else if (i < XN4 + WAN4){ src = Wa; dst = Wab; off = i - XN4; }
  else                    { src = Wp; dst = Wpb; off = i - XN4 - WAN4; }
  float4 f = reinterpret_cast<const float4*>(src)[off];
  ushort4 o;
  o.x = f2b(f.x); o.y = f2b(f.y); o.z = f2b(f.z); o.w = f2b(f.w);
  reinterpret_cast<ushort4*>(dst)[off] = o;
}

// C = A * B^T.  A: [M][K] bf16 row-major, Bm: [N][K] bf16 row-major.
// global_load_lds width=16 staging with XOR-swizzled chunk layout.
// mode 0: qkv scatter -> Qb(*scale2)/Kb [B,H,T,D], Vt [B,H,D,T] (bf16)
// mode 1: fp32 row-major [M][N] to outf
#define BM 128
#define BN 128
#define BK 64

__global__ __launch_bounds__(256, 2)
void gemm_nt(const unsigned short* __restrict__ A,
             const unsigned short* __restrict__ Bm,
             int M, int N, int K, int mode,
             unsigned short* __restrict__ qb,
             unsigned short* __restrict__ kb_,
             unsigned short* __restrict__ vt,
             float* __restrict__ outf) {
  __shared__ unsigned short As[BM * BK];  // 16 KB
  __shared__ unsigned short Bs[BN * BK];  // 16 KB
  int tid = threadIdx.x;
  int wave = tid >> 6, lane = tid & 63;
  int quad = lane >> 4, l16 = lane & 15;
  int m0 = blockIdx.x * BM, n0 = blockIdx.y * BN;
  int wm = (wave & 1) * 64, wn = (wave >> 1) * 64;

  int srow = lane >> 3;                   // 0..7
  int scol = ((lane & 7) ^ srow) << 3;    // swizzled global chunk * 8 elems

  f32x4 acc[4][4] = {};

  for (int k0 = 0; k0 < K; k0 += BK) {
    __syncthreads();
#pragma unroll
    for (int i = 0; i < 4; ++i) {
      int r = wave * 32 + i * 8;
      __builtin_amdgcn_global_load_lds(
          (const __attribute__((address_space(1))) unsigned int*)(A + (size_t)(m0 + r + srow) * K + k0 + scol),
          (__attribute__((address_space(3))) unsigned int*)(As + r * BK), 16, 0, 0);
      __builtin_amdgcn_global_load_lds(
          (const __attribute__((address_space(1))) unsigned int*)(Bm + (size_t)(n0 + r + srow) * K + k0 + scol),
          (__attribute__((address_space(3))) unsigned int*)(Bs + r * BK), 16, 0, 0);
    }
    __syncthreads();
#pragma unroll
    for (int kb = 0; kb < 2; ++kb) {
      int ch = (((kb << 2) | quad) ^ (l16 & 7)) << 3;  // swizzled chunk offset (elems)
      bf16x8 af[4], bf[4];
#pragma unroll
      for (int i = 0; i < 4; ++i)
        af[i] = *reinterpret_cast<const bf16x8*>(As + (wm + i * 16 + l16) * BK + ch);
#pragma unroll
      for (int j = 0; j < 4; ++j)
        bf[j] = *reinterpret_cast<const bf16x8*>(Bs + (wn + j * 16 + l16) * BK + ch);
#pragma unroll
      for (int i = 0; i < 4; ++i)
#pragma unroll
        for (int j = 0; j < 4; ++j)
          acc[i][j] = __builtin_amdgcn_mfma_f32_16x16x32_bf16(af[i], bf[j], acc[i][j], 0, 0, 0);
    }
  }

  const float scale2 = 0.125f * 1.44269504089f;  // 1/sqrt(64) * log2(e), folded into Q
  // epilogue: C/D layout col = l16, row = quad*4 + r  [measured m89/m91]
#pragma unroll
  for (int i = 0; i < 4; ++i) {
    int mbase = m0 + wm + i * 16 + quad * 4;
#pragma unroll
    for (int j = 0; j < 4; ++j) {
      int f = n0 + wn + j * 16 + l16;
#pragma unroll
      for (int r = 0; r < 4; ++r) {
        float c = acc[i][j][r];
        int m = mbase + r;
        if (mode == 0) {
          int b = m >> 11, t = m & 2047;          // T = 2048
          int which = f / 768;
          int f2 = f - which * 768;
          int h = f2 >> 6, d = f2 & 63;
          int bh = b * 12 + h;
          if (which == 0)      qb[((size_t)(bh * 2048 + t)) * 64 + d] = f2b(c * scale2);
          else if (which == 1) kb_[((size_t)(bh * 2048 + t)) * 64 + d] = f2b(c);
          else                 vt[((size_t)(bh * 64 + d)) * 2048 + t] = f2b(c);
        } else {
          outf[(size_t)m * N + f] = c;
        }
      }
    }
  }
}

// ---------------- Flash attention: barrier-free, LDS-free waves -----------
// Work item = (bh, qb, chunk) as before (960 blocks, 40 chunks/bh), but each
// wave is fully independent: K/V MFMA fragments are contiguous 16B slices of
// Kb / Vt, loaded straight from global (L2 serves the 4x intra-block reuse).
// No LDS, no barriers, no vmcnt drains; masked tiles simply aren't looped
// over (tlim). XCD-grouped block swizzle keeps each bh's ~0.8MB K/V/Q set in
// one XCD's L2 (3 bh per XCD). Swapped QK^T (S^T = mfma(K,Q)) with the
// verified v_cvt_pk + ds_bpermute in-register repack (R4, passed). Each
// block streams its fp32 O/L partial slab; attn_combine sums <=4 slabs.
// launch_bounds(256,3): 168-VGPR cap, no spills, 12 waves/CU.
__global__ __launch_bounds__(256, 3)
void attn_part(const unsigned short* __restrict__ Qb,
               const unsigned short* __restrict__ Kb,
               const unsigned short* __restrict__ Vt,
               float* __restrict__ Opart, float* __restrict__ Lpart) {
  const int T = 2048, D = 64;
  int lane = threadIdx.x & 63;
  int wave = threadIdx.x >> 6;
  int quad = lane >> 4, l16 = lane & 15;

  // XCD-grouped decode: 960 = 8 XCDs x 120 consecutive work items, so all
  // chunks of a given bh land on one XCD. Within an XCD: bh ascending,
  // heavy chunks first (r reversed). Bijective (960 % 8 == 0).
  int w = (blockIdx.x & 7) * 120 + (blockIdx.x >> 3);
  int bh = w / 40;
  int r = 39 - (w - bh * 40);
  int qb, ci;
  if (r < 4)       { qb = r;                 ci = 0; }
  else if (r < 12) { qb = 4 + ((r - 4) >> 1);  ci = (r - 4) & 1; }
  else if (r < 24) { qb = 8 + (r - 12) / 3;    ci = (r - 12) % 3; }
  else             { qb = 12 + ((r - 24) >> 2); ci = (r - 24) & 3; }
  int nk = 2 * qb + 2;            // causal k-tiles for this q-block
  int nc = (qb >> 2) + 1;         // chunks for this q-block
  int t0 = ci * nk / nc, t1 = (ci + 1) * nk / nc;

  int q0 = qb * 128;
  int qrow = q0 + wave * 32;              // this wave's 32 Q-rows
  int tcl = ((qrow + 31) >> 6) + 1;       // causal tile limit for this wave
  int tlim = t1 < tcl ? t1 : tcl;

  const unsigned short* Qp = Qb + (size_t)bh * T * D;
  const unsigned short* Kp = Kb + (size_t)bh * T * D;
  const unsigned short* Vp = Vt + (size_t)bh * D * T;

  // Q fragments; used as the MFMA *B* operand (n = q = l16, k = quad*8+e).
  // Qb pre-scaled by scale*log2e in gemm1 epilogue.
  bf16x8 aq[2][2];
#pragma unroll
  for (int qi = 0; qi < 2; ++qi)
#pragma unroll
    for (int cc = 0; cc < 2; ++cc)
      aq[qi][cc] = *reinterpret_cast<const bf16x8*>(
          Qp + (qrow + qi * 16 + l16) * D + cc * 32 + quad * 8);

  bf16x8 ones;
#pragma unroll
  for (int e = 0; e < 8; ++e) ones[e] = (short)0x3F80;  // bf16 1.0

  f32x4 o[2][4] = {};
  f32x4 lacc[2] = {};

  // quad-exchange constants for the P repack
  int hi = (lane >> 5) & 1;                      // quad bit1
  int adr0 = (((lane >> 4) & 1) * 32 + l16) << 2;       // w1=0 source lane*4
  int adr1 = adr0 + (16 << 2);                          // w1=1

  for (int t = t0; t < tlim; ++t) {
    int k0 = t << 6;
    const unsigned short* Kt = Kp + (size_t)k0 * D;

    // ---- K fragments straight from global: lane reads
    // K[k0 + kt*16 + l16][cc*32 + quad*8 .. +7] (16B aligned) ----
    bf16x8 ak[4][2];
#pragma unroll
    for (int kt = 0; kt < 4; ++kt)
#pragma unroll
      for (int cc = 0; cc < 2; ++cc)
        ak[kt][cc] = *reinterpret_cast<const bf16x8*>(
            Kt + (kt * 16 + l16) * D + cc * 32 + quad * 8);

    // ---- S^T = K Q^T : st[kt][qi], lane holds key = k0+kt*16+quad*4+r,
    // q = qrow+qi*16+l16 ----
    f32x4 st[4][2] = {};
    __builtin_amdgcn_s_setprio(1);
#pragma unroll
    for (int kt = 0; kt < 4; ++kt)
#pragma unroll
      for (int qi = 0; qi < 2; ++qi) {
        st[kt][qi] = __builtin_amdgcn_mfma_f32_16x16x32_bf16(ak[kt][0], aq[qi][0], st[kt][qi], 0, 0, 0);
        st[kt][qi] = __builtin_amdgcn_mfma_f32_16x16x32_bf16(ak[kt][1], aq[qi][1], st[kt][qi], 0, 0, 0);
      }
    __builtin_amdgcn_s_setprio(0);

    // ---- V fragments (issue now; latency lands under mask/exp/repack):
    // lane reads Vt[dt*16 + l16][k0 + g*32 + quad*8 .. +7] ----
    bf16x8 vf[4][2];
#pragma unroll
    for (int dt = 0; dt < 4; ++dt)
#pragma unroll
      for (int g = 0; g < 2; ++g)
        vf[dt][g] = *reinterpret_cast<const bf16x8*>(
            Vp + (size_t)(dt * 16 + l16) * T + k0 + g * 32 + quad * 8);

    // ---- causal mask only on diagonal-straddling tiles ----
    if (k0 + 63 > qrow) {
#pragma unroll
      for (int kt = 0; kt < 4; ++kt)
#pragma unroll
        for (int qi = 0; qi < 2; ++qi) {
          int q = qrow + qi * 16 + l16;
#pragma unroll
          for (int rr = 0; rr < 4; ++rr) {
            int key = k0 + kt * 16 + quad * 4 + rr;
            st[kt][qi][rr] = (key <= q) ? st[kt][qi][rr] : -1e30f;
          }
        }
    }
    // ---- p = 2^s (v_exp_f32 via builtin) ----
#pragma unroll
    for (int kt = 0; kt < 4; ++kt)
#pragma unroll
      for (int qi = 0; qi < 2; ++qi)
#pragma unroll
        for (int rr = 0; rr < 4; ++rr)
          st[kt][qi][rr] = __builtin_amdgcn_exp2f(st[kt][qi][rr]);

    // ---- in-register repack: P^T -> PV A-fragments ----
    // pa[qi][g] word w(=2*w1+w0), lane quad'=2hi+lo: keys 32g+8quad'+2w+b
    // come from register pk[2g+hi][w0] of source lane (2lo+w1)*16+l16
    // (derivation: 16kt+4qs+2h+b = 32g+8quad'+4w1+2w0+b)  [verified R4]
    bf16x8 pa[2][2];
#pragma unroll
    for (int qi = 0; qi < 2; ++qi) {
      int pk[4][2];
#pragma unroll
      for (int kt = 0; kt < 4; ++kt)
#pragma unroll
        for (int h = 0; h < 2; ++h)
          asm("v_cvt_pk_bf16_f32 %0, %1, %2"
              : "=v"(pk[kt][h])
              : "v"(st[kt][qi][2 * h]), "v"(st[kt][qi][2 * h + 1]));
#pragma unroll
      for (int g = 0; g < 2; ++g) {
        int wv[4];
#pragma unroll
        for (int w1 = 0; w1 < 2; ++w1)
#pragma unroll
          for (int w0 = 0; w0 < 2; ++w0) {
            int a_ = w1 ? adr1 : adr0;
            int r0_ = __builtin_amdgcn_ds_bpermute(a_, pk[2 * g + 0][w0]);
            int r1_ = __builtin_amdgcn_ds_bpermute(a_, pk[2 * g + 1][w0]);
            wv[w1 * 2 + w0] = hi ? r1_ : r0_;
          }
        union { int i[4]; bf16x8 v; } u_;
        u_.i[0] = wv[0]; u_.i[1] = wv[1]; u_.i[2] = wv[2]; u_.i[3] = wv[3];
        pa[qi][g] = u_.v;
      }
    }

    // ---- O += P V ; l += P * ones ----
    __builtin_amdgcn_s_setprio(1);
#pragma unroll
    for (int qi = 0; qi < 2; ++qi) {
#pragma unroll
      for (int dt = 0; dt < 4; ++dt) {
        o[qi][dt] = __builtin_amdgcn_mfma_f32_16x16x32_bf16(pa[qi][0], vf[dt][0], o[qi][dt], 0, 0, 0);
        o[qi][dt] = __builtin_amdgcn_mfma_f32_16x16x32_bf16(pa[qi][1], vf[dt][1], o[qi][dt], 0, 0, 0);
      }
      lacc[qi] = __builtin_amdgcn_mfma_f32_16x16x32_bf16(pa[qi][0], ones, lacc[qi], 0, 0, 0);
      lacc[qi] = __builtin_amdgcn_mfma_f32_16x16x32_bf16(pa[qi][1], ones, lacc[qi], 0, 0, 0);
    }
    __builtin_amdgcn_s_setprio(0);
  }

  // epilogue: stream raw O/L partials (fp32) to this work item's slab.
  // NOTE: slab index is the decoded work-item id w (combine maps by w).
  float* Op = Opart + (size_t)w * 8192 + wave * 32 * 64;
#pragma unroll
  for (int qi = 0; qi < 2; ++qi)
#pragma unroll
    for (int dt = 0; dt < 4; ++dt)
#pragma unroll
      for (int rr = 0; rr < 4; ++rr)
        Op[(qi * 16 + quad * 4 + rr) * 64 + dt * 16 + l16] = o[qi][dt][rr];
  if (l16 == 0) {
#pragma unroll
    for (int qi = 0; qi < 2; ++qi)
#pragma unroll
      for (int rr = 0; rr < 4; ++rr)
        Lpart[w * 128 + wave * 32 + qi * 16 + quad * 4 + rr] = lacc[qi][rr];
  }
}

// Sum partial chunks for each (bh,qb), normalize, write Yb [B,T,C] bf16.
__global__ __launch_bounds__(256)
void attn_combine(const float* __restrict__ Opart, const float* __restrict__ Lpart,
                  unsigned short* __restrict__ Yb) {
  int blk = blockIdx.x;            // 0..383 = (bh, qb)
  int bh = blk >> 4, qb = blk & 15;
  int off = (qb < 4) ? qb : (qb < 8) ? 4 + 2 * (qb - 4)
          : (qb < 12) ? 12 + 3 * (qb - 8) : 24 + 4 * (qb - 12);
  int nc = (qb >> 2) + 1;
  // attn_part used r-reversed ordering: chunk r in [off, off+nc) maps to
  // work item bh*40 + (39 - r)
  int b = bh / 12, h = bh - b * 12;
  int q0 = qb * 128;
#pragma unroll
  for (int i = 0; i < 8; ++i) {
    int idx = i * 256 + threadIdx.x;     // 0..2047 over 128 rows x 16 float4
    int row = idx >> 4, c4 = idx & 15;
    float4 s = {0.f, 0.f, 0.f, 0.f};
    float L = 0.f;
    for (int ci = 0; ci < nc; ++ci) {
      size_t pb = (size_t)(bh * 40 + 39 - (off + ci));
      float4 v = *reinterpret_cast<const float4*>(Opart + pb * 8192 + row * 64 + c4 * 4);
      s.x += v.x; s.y += v.y; s.z += v.z; s.w += v.w;
      L += Lpart[pb * 128 + row];
    }
    float rl = 1.0f / L;
    ushort4 y;
    y.x = f2b(s.x * rl); y.y = f2b(s.y * rl);
    y.z = f2b(s.z * rl); y.w = f2b(s.w * rl);
    *reinterpret_cast<ushort4*>(Yb + ((size_t)(b * 2048 + q0 + row)) * 768 + h * 64 + c4 * 4) = y;
  }
}

extern "C" void kernel_launch(void* const* d_in, const int* in_sizes, int n_in,
                              void* d_out, int out_size, void* d_ws, size_t ws_size,
                              hipStream_t stream) {
  const float* x  = (const float*)d_in[0];   // [2,2048,768]
  const float* Wa = (const float*)d_in[1];   // [2304,768]
  const float* Wp = (const float*)d_in[2];   // [768,768]
  float* out = (float*)d_out;                // [2,2048,768] fp32

  unsigned short* ws = (unsigned short*)d_ws;
  unsigned short* xb  = ws;                  // 4096*768
  unsigned short* Wab = xb  + 3145728;       // 2304*768
  unsigned short* Wpb = Wab + 1769472;       // 768*768
  unsigned short* Qb  = Wpb + 589824;        // 24*2048*64 (pre-scaled)
  unsigned short* Kb  = Qb  + 3145728;
  unsigned short* Vt  = Kb  + 3145728;       // [24][64][2048]
  unsigned short* Yb  = Vt  + 3145728;       // 4096*768
  float*          Opart = (float*)(Yb + 3145728);  // 960*128*64 fp32
  float*          Lpart = Opart + 7864320;         // 960*128 fp32

  cvt_all<<<(XN4 + WAN4 + WPN4) / 256, 256, 0, stream>>>(x, Wa, Wp, xb, Wab, Wpb);

  gemm_nt<<<dim3(4096 / BM, 2304 / BN), 256, 0, stream>>>(
      xb, Wab, 4096, 2304, 768, 0, Qb, Kb, Vt, nullptr);

  attn_part<<<960, 256, 0, stream>>>(Qb, Kb, Vt, Opart, Lpart);
  attn_combine<<<384, 256, 0, stream>>>(Opart, Lpart, Yb);

  gemm_nt<<<dim3(4096 / BM, 768 / BN), 256, 0, stream>>>(
      Yb, Wpb, 4096, 768, 768, 1, nullptr, nullptr, nullptr, out);
}

// Round 6
// 156.350 us; speedup vs baseline: 1.2458x; 1.2458x over previous
//
#include <hip/hip_runtime.h>

typedef __attribute__((ext_vector_type(8))) short bf16x8;
typedef __attribute__((ext_vector_type(4))) float f32x4;

// fp32 -> bf16 (round-to-nearest-even), finite inputs only
__device__ __forceinline__ unsigned short f2b(float f) {
  union { float f; unsigned u; } v; v.f = f;
  return (unsigned short)((v.u + 0x7FFFu + ((v.u >> 16) & 1u)) >> 16);
}

// Fused fp32->bf16 cast for x, W_attn, W_proj (one launch)
#define XN4   786432   // 4096*768/4
#define WAN4  442368   // 2304*768/4
#define WPN4  147456   // 768*768/4
__global__ void cvt_all(const float* __restrict__ x, const float* __restrict__ Wa,
                        const float* __restrict__ Wp,
                        unsigned short* __restrict__ xb, unsigned short* __restrict__ Wab,
                        unsigned short* __restrict__ Wpb) {
  int i = blockIdx.x * 256 + threadIdx.x;
  const float* src; unsigned short* dst; int off;
  if (i < XN4)            { src = x;  dst = xb;  off = i; }
  else if (i < XN4 + WAN4){ src = Wa; dst = Wab; off = i - XN4; }
  else                    { src = Wp; dst = Wpb; off = i - XN4 - WAN4; }
  float4 f = reinterpret_cast<const float4*>(src)[off];
  ushort4 o;
  o.x = f2b(f.x); o.y = f2b(f.y); o.z = f2b(f.z); o.w = f2b(f.w);
  reinterpret_cast<ushort4*>(dst)[off] = o;
}

// C = A * B^T.  A: [M][K] bf16 row-major, Bm: [N][K] bf16 row-major.
// global_load_lds width=16 staging with XOR-swizzled chunk layout.
// mode 0: qkv scatter -> Qb(*scale2)/Kb [B,H,T,D], Vt [B,H,D,T] (bf16)
// mode 1: fp32 row-major [M][N] to outf
#define BM 128
#define BN 128
#define BK 64

__global__ __launch_bounds__(256, 2)
void gemm_nt(const unsigned short* __restrict__ A,
             const unsigned short* __restrict__ Bm,
             int M, int N, int K, int mode,
             unsigned short* __restrict__ qb,
             unsigned short* __restrict__ kb_,
             unsigned short* __restrict__ vt,
             float* __restrict__ outf) {
  __shared__ unsigned short As[BM * BK];  // 16 KB
  __shared__ unsigned short Bs[BN * BK];  // 16 KB
  int tid = threadIdx.x;
  int wave = tid >> 6, lane = tid & 63;
  int quad = lane >> 4, l16 = lane & 15;
  int m0 = blockIdx.x * BM, n0 = blockIdx.y * BN;
  int wm = (wave & 1) * 64, wn = (wave >> 1) * 64;

  int srow = lane >> 3;                   // 0..7
  int scol = ((lane & 7) ^ srow) << 3;    // swizzled global chunk * 8 elems

  f32x4 acc[4][4] = {};

  for (int k0 = 0; k0 < K; k0 += BK) {
    __syncthreads();
#pragma unroll
    for (int i = 0; i < 4; ++i) {
      int r = wave * 32 + i * 8;
      __builtin_amdgcn_global_load_lds(
          (const __attribute__((address_space(1))) unsigned int*)(A + (size_t)(m0 + r + srow) * K + k0 + scol),
          (__attribute__((address_space(3))) unsigned int*)(As + r * BK), 16, 0, 0);
      __builtin_amdgcn_global_load_lds(
          (const __attribute__((address_space(1))) unsigned int*)(Bm + (size_t)(n0 + r + srow) * K + k0 + scol),
          (__attribute__((address_space(3))) unsigned int*)(Bs + r * BK), 16, 0, 0);
    }
    __syncthreads();
#pragma unroll
    for (int kb = 0; kb < 2; ++kb) {
      int ch = (((kb << 2) | quad) ^ (l16 & 7)) << 3;  // swizzled chunk offset (elems)
      bf16x8 af[4], bf[4];
#pragma unroll
      for (int i = 0; i < 4; ++i)
        af[i] = *reinterpret_cast<const bf16x8*>(As + (wm + i * 16 + l16) * BK + ch);
#pragma unroll
      for (int j = 0; j < 4; ++j)
        bf[j] = *reinterpret_cast<const bf16x8*>(Bs + (wn + j * 16 + l16) * BK + ch);
#pragma unroll
      for (int i = 0; i < 4; ++i)
#pragma unroll
        for (int j = 0; j < 4; ++j)
          acc[i][j] = __builtin_amdgcn_mfma_f32_16x16x32_bf16(af[i], bf[j], acc[i][j], 0, 0, 0);
    }
  }

  const float scale2 = 0.125f * 1.44269504089f;  // 1/sqrt(64) * log2(e), folded into Q
  // epilogue: C/D layout col = l16, row = quad*4 + r  [measured m89/m91]
#pragma unroll
  for (int i = 0; i < 4; ++i) {
    int mbase = m0 + wm + i * 16 + quad * 4;
#pragma unroll
    for (int j = 0; j < 4; ++j) {
      int f = n0 + wn + j * 16 + l16;
#pragma unroll
      for (int r = 0; r < 4; ++r) {
        float c = acc[i][j][r];
        int m = mbase + r;
        if (mode == 0) {
          int b = m >> 11, t = m & 2047;          // T = 2048
          int which = f / 768;
          int f2 = f - which * 768;
          int h = f2 >> 6, d = f2 & 63;
          int bh = b * 12 + h;
          if (which == 0)      qb[((size_t)(bh * 2048 + t)) * 64 + d] = f2b(c * scale2);
          else if (which == 1) kb_[((size_t)(bh * 2048 + t)) * 64 + d] = f2b(c);
          else                 vt[((size_t)(bh * 64 + d)) * 2048 + t] = f2b(c);
        } else {
          outf[(size_t)m * N + f] = c;
        }
      }
    }
  }
}

// ---------------- Flash attention, chunked deterministic split-K ----------
// R6 = R4's passed kernel (LDS double-buffer staging + swapped QK^T with
// in-register v_cvt_pk + ds_bpermute repack) with two verified deltas:
//  (a) __launch_bounds__(256,3): 168-VGPR cap -> no scratch spills (R4's
//      regression was spill traffic under the 128 cap);
//  (b) R5's XCD-grouped block decode + slab-by-w epilogue: all 40 chunks of
//      a bh stay on one XCD -> K/V/Q served from that XCD's L2 (R5 measured
//      FETCH 9.3MB vs 42-58MB without).
// 960 blocks, LDS 32KB, 3 blocks/CU by VGPR; attn_combine sums <=4 slabs.
__global__ __launch_bounds__(256, 3)
void attn_part(const unsigned short* __restrict__ Qb,
               const unsigned short* __restrict__ Kb,
               const unsigned short* __restrict__ Vt,
               float* __restrict__ Opart, float* __restrict__ Lpart) {
  __shared__ unsigned short Ks[2][64 * 64];   // 2 x 8 KB, swizzled chunks
  __shared__ unsigned short Vs[2][64 * 64];   // 2 x 8 KB
  const int T = 2048, D = 64;
  int lane = threadIdx.x & 63;
  int wave = threadIdx.x >> 6;
  int quad = lane >> 4, l16 = lane & 15;

  // XCD-grouped decode: 960 = 8 XCDs x 120 consecutive work items, so all
  // chunks of a given bh land on one XCD. Within an XCD: bh ascending,
  // heavy chunks first (r reversed). Bijective (960 % 8 == 0).
  int w = (blockIdx.x & 7) * 120 + (blockIdx.x >> 3);
  int bh = w / 40;
  int r = 39 - (w - bh * 40);
  int qb, ci;
  if (r < 4)       { qb = r;                 ci = 0; }
  else if (r < 12) { qb = 4 + ((r - 4) >> 1);  ci = (r - 4) & 1; }
  else if (r < 24) { qb = 8 + (r - 12) / 3;    ci = (r - 12) % 3; }
  else             { qb = 12 + ((r - 24) >> 2); ci = (r - 24) & 3; }
  int nk = 2 * qb + 2;            // causal k-tiles for this q-block
  int nc = (qb >> 2) + 1;         // chunks for this q-block
  int t0 = ci * nk / nc, t1 = (ci + 1) * nk / nc;

  int q0 = qb * 128;
  int qrow = q0 + wave * 32;        // this wave's 32 Q-rows

  const unsigned short* Qp = Qb + (size_t)bh * T * D;
  const unsigned short* Kp = Kb + (size_t)bh * T * D;
  const unsigned short* Vp = Vt + (size_t)bh * D * T;

  int srow = lane >> 3;                 // 0..7
  int scol = ((lane & 7) ^ srow) << 3;  // swizzled chunk*8 elems

  // Q fragments; used as the MFMA *B* operand (n = q = l16, k = quad*8+e).
  // Qb pre-scaled by scale*log2e in gemm1 epilogue.
  bf16x8 aq[2][2];
#pragma unroll
  for (int qi = 0; qi < 2; ++qi)
#pragma unroll
    for (int cc = 0; cc < 2; ++cc)
      aq[qi][cc] = *reinterpret_cast<const bf16x8*>(
          Qp + (qrow + qi * 16 + l16) * D + cc * 32 + quad * 8);

  bf16x8 ones;
#pragma unroll
  for (int e = 0; e < 8; ++e) ones[e] = (short)0x3F80;  // bf16 1.0

  f32x4 o[2][4] = {};
  f32x4 lacc[2] = {};

  // quad-exchange constants for the P repack
  int hi = (lane >> 5) & 1;                      // quad bit1
  int adr0 = (((lane >> 4) & 1) * 32 + l16) << 2;       // w1=0 source lane*4
  int adr1 = adr0 + (16 << 2);                          // w1=1

#define STAGE_KV(buf, k0s)                                                          \
  {                                                                                 \
    _Pragma("unroll")                                                               \
    for (int i_ = 0; i_ < 2; ++i_) {                                                \
      int rr_ = wave * 16 + i_ * 8;                                                 \
      __builtin_amdgcn_global_load_lds(                                             \
          (const __attribute__((address_space(1))) unsigned int*)(Kp + (size_t)((k0s) + rr_ + srow) * 64 + scol), \
          (__attribute__((address_space(3))) unsigned int*)(&Ks[buf][rr_ * 64]), 16, 0, 0); \
      __builtin_amdgcn_global_load_lds(                                             \
          (const __attribute__((address_space(1))) unsigned int*)(Vp + (size_t)(rr_ + srow) * 2048 + (k0s) + scol), \
          (__attribute__((address_space(3))) unsigned int*)(&Vs[buf][rr_ * 64]), 16, 0, 0); \
    }                                                                               \
  }

  // prologue: stage first tile, drain, barrier
  STAGE_KV(0, t0 << 6);
  asm volatile("s_waitcnt vmcnt(0)" ::: "memory");
  __builtin_amdgcn_s_barrier();

  int cur = 0;
  for (int t = t0; t < t1; ++t) {
    int k0 = t << 6;
    if (t + 1 < t1) STAGE_KV(cur ^ 1, (t + 1) << 6);  // issue next tile, don't wait

    if (k0 <= qrow + 31) {
      // ---- S^T = K Q^T : st[kt][qi], lane holds key = k0+kt*16+quad*4+r,
      // q = qrow+qi*16+l16 ----
      f32x4 st[4][2] = {};
      __builtin_amdgcn_s_setprio(1);
#pragma unroll
      for (int kt = 0; kt < 4; ++kt) {
        bf16x8 ak0 = *reinterpret_cast<const bf16x8*>(Ks[cur] + (kt * 16 + l16) * 64 + ((quad ^ (l16 & 7)) << 3));
        bf16x8 ak1 = *reinterpret_cast<const bf16x8*>(Ks[cur] + (kt * 16 + l16) * 64 + (((4 | quad) ^ (l16 & 7)) << 3));
#pragma unroll
        for (int qi = 0; qi < 2; ++qi) {
          st[kt][qi] = __builtin_amdgcn_mfma_f32_16x16x32_bf16(ak0, aq[qi][0], st[kt][qi], 0, 0, 0);
          st[kt][qi] = __builtin_amdgcn_mfma_f32_16x16x32_bf16(ak1, aq[qi][1], st[kt][qi], 0, 0, 0);
        }
      }
      __builtin_amdgcn_s_setprio(0);

      // ---- causal mask only on diagonal-straddling tiles ----
      if (k0 + 63 > qrow) {
#pragma unroll
        for (int kt = 0; kt < 4; ++kt)
#pragma unroll
          for (int qi = 0; qi < 2; ++qi) {
            int q = qrow + qi * 16 + l16;
#pragma unroll
            for (int rr = 0; rr < 4; ++rr) {
              int key = k0 + kt * 16 + quad * 4 + rr;
              st[kt][qi][rr] = (key <= q) ? st[kt][qi][rr] : -1e30f;
            }
          }
      }
      // ---- p = 2^s (v_exp_f32 via builtin) ----
#pragma unroll
      for (int kt = 0; kt < 4; ++kt)
#pragma unroll
        for (int qi = 0; qi < 2; ++qi)
#pragma unroll
          for (int rr = 0; rr < 4; ++rr)
            st[kt][qi][rr] = __builtin_amdgcn_exp2f(st[kt][qi][rr]);

      // ---- V fragments (issue early; latency hides under repack) ----
      bf16x8 vf[4][2];
#pragma unroll
      for (int dt = 0; dt < 4; ++dt) {
        vf[dt][0] = *reinterpret_cast<const bf16x8*>(Vs[cur] + (dt * 16 + l16) * 64 + ((quad ^ (l16 & 7)) << 3));
        vf[dt][1] = *reinterpret_cast<const bf16x8*>(Vs[cur] + (dt * 16 + l16) * 64 + (((4 | quad) ^ (l16 & 7)) << 3));
      }

      // ---- in-register repack: P^T -> PV A-fragments ----
      // pa[qi][g] word w(=2*w1+w0), lane quad'=2hi+lo: keys 32g+8quad'+2w+b
      // come from register pk[2g+hi][w0] of source lane (2lo+w1)*16+l16
      // (derivation: 16kt+4qs+2h+b = 32g+8quad'+4w1+2w0+b)  [verified R4]
      bf16x8 pa[2][2];
#pragma unroll
      for (int qi = 0; qi < 2; ++qi) {
        int pk[4][2];
#pragma unroll
        for (int kt = 0; kt < 4; ++kt)
#pragma unroll
          for (int h = 0; h < 2; ++h)
            asm("v_cvt_pk_bf16_f32 %0, %1, %2"
                : "=v"(pk[kt][h])
                : "v"(st[kt][qi][2 * h]), "v"(st[kt][qi][2 * h + 1]));
#pragma unroll
        for (int g = 0; g < 2; ++g) {
          int wv[4];
#pragma unroll
          for (int w1 = 0; w1 < 2; ++w1)
#pragma unroll
            for (int w0 = 0; w0 < 2; ++w0) {
              int a_ = w1 ? adr1 : adr0;
              int r0_ = __builtin_amdgcn_ds_bpermute(a_, pk[2 * g + 0][w0]);
              int r1_ = __builtin_amdgcn_ds_bpermute(a_, pk[2 * g + 1][w0]);
              wv[w1 * 2 + w0] = hi ? r1_ : r0_;
            }
          union { int i[4]; bf16x8 v; } u_;
          u_.i[0] = wv[0]; u_.i[1] = wv[1]; u_.i[2] = wv[2]; u_.i[3] = wv[3];
          pa[qi][g] = u_.v;
        }
      }

      // ---- O += P V ; l += P * ones ----
      __builtin_amdgcn_s_setprio(1);
#pragma unroll
      for (int qi = 0; qi < 2; ++qi) {
#pragma unroll
        for (int dt = 0; dt < 4; ++dt) {
          o[qi][dt] = __builtin_amdgcn_mfma_f32_16x16x32_bf16(pa[qi][0], vf[dt][0], o[qi][dt], 0, 0, 0);
          o[qi][dt] = __builtin_amdgcn_mfma_f32_16x16x32_bf16(pa[qi][1], vf[dt][1], o[qi][dt], 0, 0, 0);
        }
        lacc[qi] = __builtin_amdgcn_mfma_f32_16x16x32_bf16(pa[qi][0], ones, lacc[qi], 0, 0, 0);
        lacc[qi] = __builtin_amdgcn_mfma_f32_16x16x32_bf16(pa[qi][1], ones, lacc[qi], 0, 0, 0);
      }
      __builtin_amdgcn_s_setprio(0);
    }

    // wait next-tile loads, then release both buffers for the next iteration
    asm volatile("s_waitcnt vmcnt(0)" ::: "memory");
    __builtin_amdgcn_s_barrier();
    cur ^= 1;
  }

  // epilogue: stream raw O/L partials (fp32) to this work item's slab.
  // Slab index is the decoded work-item id w (combine maps by w).
  float* Op = Opart + (size_t)w * 8192 + wave * 32 * 64;
#pragma unroll
  for (int qi = 0; qi < 2; ++qi)
#pragma unroll
    for (int dt = 0; dt < 4; ++dt)
#pragma unroll
      for (int rr = 0; rr < 4; ++rr)
        Op[(qi * 16 + quad * 4 + rr) * 64 + dt * 16 + l16] = o[qi][dt][rr];
  if (l16 == 0) {
#pragma unroll
    for (int qi = 0; qi < 2; ++qi)
#pragma unroll
      for (int rr = 0; rr < 4; ++rr)
        Lpart[w * 128 + wave * 32 + qi * 16 + quad * 4 + rr] = lacc[qi][rr];
  }
}

// Sum partial chunks for each (bh,qb), normalize, write Yb [B,T,C] bf16.
__global__ __launch_bounds__(256)
void attn_combine(const float* __restrict__ Opart, const float* __restrict__ Lpart,
                  unsigned short* __restrict__ Yb) {
  int blk = blockIdx.x;            // 0..383 = (bh, qb)
  int bh = blk >> 4, qb = blk & 15;
  int off = (qb < 4) ? qb : (qb < 8) ? 4 + 2 * (qb - 4)
          : (qb < 12) ? 12 + 3 * (qb - 8) : 24 + 4 * (qb - 12);
  int nc = (qb >> 2) + 1;
  // attn_part used r-reversed ordering: chunk r in [off, off+nc) maps to
  // work item bh*40 + (39 - r)
  int b = bh / 12, h = bh - b * 12;
  int q0 = qb * 128;
#pragma unroll
  for (int i = 0; i < 8; ++i) {
    int idx = i * 256 + threadIdx.x;     // 0..2047 over 128 rows x 16 float4
    int row = idx >> 4, c4 = idx & 15;
    float4 s = {0.f, 0.f, 0.f, 0.f};
    float L = 0.f;
    for (int ci = 0; ci < nc; ++ci) {
      size_t pb = (size_t)(bh * 40 + 39 - (off + ci));
      float4 v = *reinterpret_cast<const float4*>(Opart + pb * 8192 + row * 64 + c4 * 4);
      s.x += v.x; s.y += v.y; s.z += v.z; s.w += v.w;
      L += Lpart[pb * 128 + row];
    }
    float rl = 1.0f / L;
    ushort4 y;
    y.x = f2b(s.x * rl); y.y = f2b(s.y * rl);
    y.z = f2b(s.z * rl); y.w = f2b(s.w * rl);
    *reinterpret_cast<ushort4*>(Yb + ((size_t)(b * 2048 + q0 + row)) * 768 + h * 64 + c4 * 4) = y;
  }
}

extern "C" void kernel_launch(void* const* d_in, const int* in_sizes, int n_in,
                              void* d_out, int out_size, void* d_ws, size_t ws_size,
                              hipStream_t stream) {
  const float* x  = (const float*)d_in[0];   // [2,2048,768]
  const float* Wa = (const float*)d_in[1];   // [2304,768]
  const float* Wp = (const float*)d_in[2];   // [768,768]
  float* out = (float*)d_out;                // [2,2048,768] fp32

  unsigned short* ws = (unsigned short*)d_ws;
  unsigned short* xb  = ws;                  // 4096*768
  unsigned short* Wab = xb  + 3145728;       // 2304*768
  unsigned short* Wpb = Wab + 1769472;       // 768*768
  unsigned short* Qb  = Wpb + 589824;        // 24*2048*64 (pre-scaled)
  unsigned short* Kb  = Qb  + 3145728;
  unsigned short* Vt  = Kb  + 3145728;       // [24][64][2048]
  unsigned short* Yb  = Vt  + 3145728;       // 4096*768
  float*          Opart = (float*)(Yb + 3145728);  // 960*128*64 fp32
  float*          Lpart = Opart + 7864320;         // 960*128 fp32

  cvt_all<<<(XN4 + WAN4 + WPN4) / 256, 256, 0, stream>>>(x, Wa, Wp, xb, Wab, Wpb);

  gemm_nt<<<dim3(4096 / BM, 2304 / BN), 256, 0, stream>>>(
      xb, Wab, 4096, 2304, 768, 0, Qb, Kb, Vt, nullptr);

  attn_part<<<960, 256, 0, stream>>>(Qb, Kb, Vt, Opart, Lpart);
  attn_combine<<<384, 256, 0, stream>>>(Opart, Lpart, Yb);

  gemm_nt<<<dim3(4096 / BM, 768 / BN), 256, 0, stream>>>(
      Yb, Wpb, 4096, 768, 768, 1, nullptr, nullptr, nullptr, out);
}

// Round 9
// 155.884 us; speedup vs baseline: 1.2495x; 1.0030x over previous
//
#include <hip/hip_runtime.h>

typedef __attribute__((ext_vector_type(8))) short bf16x8;
typedef __attribute__((ext_vector_type(4))) float f32x4;

// fp32 -> bf16 (round-to-nearest-even), finite inputs only
__device__ __forceinline__ unsigned short f2b(float f) {
  union { float f; unsigned u; } v; v.f = f;
  return (unsigned short)((v.u + 0x7FFFu + ((v.u >> 16) & 1u)) >> 16);
}

// Fused fp32->bf16 cast for x, W_attn, W_proj (one launch)
#define XN4   786432   // 4096*768/4
#define WAN4  442368   // 2304*768/4
#define WPN4  147456   // 768*768/4
__global__ void cvt_all(const float* __restrict__ x, const float* __restrict__ Wa,
                        const float* __restrict__ Wp,
                        unsigned short* __restrict__ xb, unsigned short* __restrict__ Wab,
                        unsigned short* __restrict__ Wpb) {
  int i = blockIdx.x * 256 + threadIdx.x;
  const float* src; unsigned short* dst; int off;
  if (i < XN4)            { src = x;  dst = xb;  off = i; }
  else if (i < XN4 + WAN4){ src = Wa; dst = Wab; off = i - XN4; }
  else                    { src = Wp; dst = Wpb; off = i - XN4 - WAN4; }
  float4 f = reinterpret_cast<const float4*>(src)[off];
  ushort4 o;
  o.x = f2b(f.x); o.y = f2b(f.y); o.z = f2b(f.z); o.w = f2b(f.w);
  reinterpret_cast<ushort4*>(dst)[off] = o;
}

// C = A * B^T.  A: [M][K] bf16 row-major, Bm: [N][K] bf16 row-major.
// global_load_lds width=16 staging with XOR-swizzled chunk layout.
// mode 0: qkv scatter -> Qb(*scale2)/Kb [B,H,T,D], Vt [B,H,D,T] (bf16)
// mode 1: fp32 row-major [M][N] to outf
// R9: launch_bounds (256,2) -> (256,3). The old bound force-capped the gemm
// at 2 blocks/CU; the m97-structure this kernel copies runs 3 blocks/CU
// (~130 live VGPRs < 168 cap, 32KB LDS < 160/3). Pure occupancy hint.
#define BM 128
#define BN 128
#define BK 64

__global__ __launch_bounds__(256, 3)
void gemm_nt(const unsigned short* __restrict__ A,
             const unsigned short* __restrict__ Bm,
             int M, int N, int K, int mode,
             unsigned short* __restrict__ qb,
             unsigned short* __restrict__ kb_,
             unsigned short* __restrict__ vt,
             float* __restrict__ outf) {
  __shared__ unsigned short As[BM * BK];  // 16 KB
  __shared__ unsigned short Bs[BN * BK];  // 16 KB
  int tid = threadIdx.x;
  int wave = tid >> 6, lane = tid & 63;
  int quad = lane >> 4, l16 = lane & 15;
  int m0 = blockIdx.x * BM, n0 = blockIdx.y * BN;
  int wm = (wave & 1) * 64, wn = (wave >> 1) * 64;

  int srow = lane >> 3;                   // 0..7
  int scol = ((lane & 7) ^ srow) << 3;    // swizzled global chunk * 8 elems

  f32x4 acc[4][4] = {};

  for (int k0 = 0; k0 < K; k0 += BK) {
    __syncthreads();
#pragma unroll
    for (int i = 0; i < 4; ++i) {
      int r = wave * 32 + i * 8;
      __builtin_amdgcn_global_load_lds(
          (const __attribute__((address_space(1))) unsigned int*)(A + (size_t)(m0 + r + srow) * K + k0 + scol),
          (__attribute__((address_space(3))) unsigned int*)(As + r * BK), 16, 0, 0);
      __builtin_amdgcn_global_load_lds(
          (const __attribute__((address_space(1))) unsigned int*)(Bm + (size_t)(n0 + r + srow) * K + k0 + scol),
          (__attribute__((address_space(3))) unsigned int*)(Bs + r * BK), 16, 0, 0);
    }
    __syncthreads();
#pragma unroll
    for (int kb = 0; kb < 2; ++kb) {
      int ch = (((kb << 2) | quad) ^ (l16 & 7)) << 3;  // swizzled chunk offset (elems)
      bf16x8 af[4], bf[4];
#pragma unroll
      for (int i = 0; i < 4; ++i)
        af[i] = *reinterpret_cast<const bf16x8*>(As + (wm + i * 16 + l16) * BK + ch);
#pragma unroll
      for (int j = 0; j < 4; ++j)
        bf[j] = *reinterpret_cast<const bf16x8*>(Bs + (wn + j * 16 + l16) * BK + ch);
#pragma unroll
      for (int i = 0; i < 4; ++i)
#pragma unroll
        for (int j = 0; j < 4; ++j)
          acc[i][j] = __builtin_amdgcn_mfma_f32_16x16x32_bf16(af[i], bf[j], acc[i][j], 0, 0, 0);
    }
  }

  const float scale2 = 0.125f * 1.44269504089f;  // 1/sqrt(64) * log2(e), folded into Q
  // epilogue: C/D layout col = l16, row = quad*4 + r  [measured m89/m91]
#pragma unroll
  for (int i = 0; i < 4; ++i) {
    int mbase = m0 + wm + i * 16 + quad * 4;
#pragma unroll
    for (int j = 0; j < 4; ++j) {
      int f = n0 + wn + j * 16 + l16;
#pragma unroll
      for (int r = 0; r < 4; ++r) {
        float c = acc[i][j][r];
        int m = mbase + r;
        if (mode == 0) {
          int b = m >> 11, t = m & 2047;          // T = 2048
          int which = f / 768;
          int f2 = f - which * 768;
          int h = f2 >> 6, d = f2 & 63;
          int bh = b * 12 + h;
          if (which == 0)      qb[((size_t)(bh * 2048 + t)) * 64 + d] = f2b(c * scale2);
          else if (which == 1) kb_[((size_t)(bh * 2048 + t)) * 64 + d] = f2b(c);
          else                 vt[((size_t)(bh * 64 + d)) * 2048 + t] = f2b(c);
        } else {
          outf[(size_t)m * N + f] = c;
        }
      }
    }
  }
}

// ---------------- Flash attention, chunked deterministic split-K ----------
// R9 attn = R6's exact passing kernel (156.3us): 2-buffer LDS double-buffer,
// vmcnt(0)+barrier per tile, swapped QK^T with in-register v_cvt_pk +
// ds_bpermute repack, XCD-grouped decode, slab-by-w epilogue.
// (R7/R8's 3-buffer counted-vmcnt pipeline failed correctness twice on HW
// despite a clean paper ledger — reverted; see session journal.)
__global__ __launch_bounds__(256, 3)
void attn_part(const unsigned short* __restrict__ Qb,
               const unsigned short* __restrict__ Kb,
               const unsigned short* __restrict__ Vt,
               float* __restrict__ Opart, float* __restrict__ Lpart) {
  __shared__ unsigned short Ks[2][64 * 64];   // 2 x 8 KB, swizzled chunks
  __shared__ unsigned short Vs[2][64 * 64];   // 2 x 8 KB
  const int T = 2048, D = 64;
  int lane = threadIdx.x & 63;
  int wave = threadIdx.x >> 6;
  int quad = lane >> 4, l16 = lane & 15;

  // XCD-grouped decode: 960 = 8 XCDs x 120 consecutive work items, so all
  // chunks of a given bh land on one XCD. Within an XCD: bh ascending,
  // heavy chunks first (r reversed). Bijective (960 % 8 == 0).
  int w = (blockIdx.x & 7) * 120 + (blockIdx.x >> 3);
  int bh = w / 40;
  int r = 39 - (w - bh * 40);
  int qb, ci;
  if (r < 4)       { qb = r;                 ci = 0; }
  else if (r < 12) { qb = 4 + ((r - 4) >> 1);  ci = (r - 4) & 1; }
  else if (r < 24) { qb = 8 + (r - 12) / 3;    ci = (r - 12) % 3; }
  else             { qb = 12 + ((r - 24) >> 2); ci = (r - 24) & 3; }
  int nk = 2 * qb + 2;            // causal k-tiles for this q-block
  int nc = (qb >> 2) + 1;         // chunks for this q-block
  int t0 = ci * nk / nc, t1 = (ci + 1) * nk / nc;

  int q0 = qb * 128;
  int qrow = q0 + wave * 32;        // this wave's 32 Q-rows

  const unsigned short* Qp = Qb + (size_t)bh * T * D;
  const unsigned short* Kp = Kb + (size_t)bh * T * D;
  const unsigned short* Vp = Vt + (size_t)bh * D * T;

  int srow = lane >> 3;                 // 0..7
  int scol = ((lane & 7) ^ srow) << 3;  // swizzled chunk*8 elems

  // Q fragments; used as the MFMA *B* operand (n = q = l16, k = quad*8+e).
  // Qb pre-scaled by scale*log2e in gemm1 epilogue.
  bf16x8 aq[2][2];
#pragma unroll
  for (int qi = 0; qi < 2; ++qi)
#pragma unroll
    for (int cc = 0; cc < 2; ++cc)
      aq[qi][cc] = *reinterpret_cast<const bf16x8*>(
          Qp + (qrow + qi * 16 + l16) * D + cc * 32 + quad * 8);

  bf16x8 ones;
#pragma unroll
  for (int e = 0; e < 8; ++e) ones[e] = (short)0x3F80;  // bf16 1.0

  f32x4 o[2][4] = {};
  f32x4 lacc[2] = {};

  // quad-exchange constants for the P repack
  int hi = (lane >> 5) & 1;                      // quad bit1
  int adr0 = (((lane >> 4) & 1) * 32 + l16) << 2;       // w1=0 source lane*4
  int adr1 = adr0 + (16 << 2);                          // w1=1

#define STAGE_KV(buf, k0s)                                                          \
  {                                                                                 \
    _Pragma("unroll")                                                               \
    for (int i_ = 0; i_ < 2; ++i_) {                                                \
      int rr_ = wave * 16 + i_ * 8;                                                 \
      __builtin_amdgcn_global_load_lds(                                             \
          (const __attribute__((address_space(1))) unsigned int*)(Kp + (size_t)((k0s) + rr_ + srow) * 64 + scol), \
          (__attribute__((address_space(3))) unsigned int*)(&Ks[buf][rr_ * 64]), 16, 0, 0); \
      __builtin_amdgcn_global_load_lds(                                             \
          (const __attribute__((address_space(1))) unsigned int*)(Vp + (size_t)(rr_ + srow) * 2048 + (k0s) + scol), \
          (__attribute__((address_space(3))) unsigned int*)(&Vs[buf][rr_ * 64]), 16, 0, 0); \
    }                                                                               \
  }

  // prologue: stage first tile, drain, barrier
  STAGE_KV(0, t0 << 6);
  asm volatile("s_waitcnt vmcnt(0)" ::: "memory");
  __builtin_amdgcn_s_barrier();

  int cur = 0;
  for (int t = t0; t < t1; ++t) {
    int k0 = t << 6;
    if (t + 1 < t1) STAGE_KV(cur ^ 1, (t + 1) << 6);  // issue next tile, don't wait

    if (k0 <= qrow + 31) {
      // ---- S^T = K Q^T : st[kt][qi], lane holds key = k0+kt*16+quad*4+r,
      // q = qrow+qi*16+l16 ----
      f32x4 st[4][2] = {};
      __builtin_amdgcn_s_setprio(1);
#pragma unroll
      for (int kt = 0; kt < 4; ++kt) {
        bf16x8 ak0 = *reinterpret_cast<const bf16x8*>(Ks[cur] + (kt * 16 + l16) * 64 + ((quad ^ (l16 & 7)) << 3));
        bf16x8 ak1 = *reinterpret_cast<const bf16x8*>(Ks[cur] + (kt * 16 + l16) * 64 + (((4 | quad) ^ (l16 & 7)) << 3));
#pragma unroll
        for (int qi = 0; qi < 2; ++qi) {
          st[kt][qi] = __builtin_amdgcn_mfma_f32_16x16x32_bf16(ak0, aq[qi][0], st[kt][qi], 0, 0, 0);
          st[kt][qi] = __builtin_amdgcn_mfma_f32_16x16x32_bf16(ak1, aq[qi][1], st[kt][qi], 0, 0, 0);
        }
      }
      __builtin_amdgcn_s_setprio(0);

      // ---- causal mask only on diagonal-straddling tiles ----
      if (k0 + 63 > qrow) {
#pragma unroll
        for (int kt = 0; kt < 4; ++kt)
#pragma unroll
          for (int qi = 0; qi < 2; ++qi) {
            int q = qrow + qi * 16 + l16;
#pragma unroll
            for (int rr = 0; rr < 4; ++rr) {
              int key = k0 + kt * 16 + quad * 4 + rr;
              st[kt][qi][rr] = (key <= q) ? st[kt][qi][rr] : -1e30f;
            }
          }
      }
      // ---- p = 2^s (v_exp_f32 via builtin) ----
#pragma unroll
      for (int kt = 0; kt < 4; ++kt)
#pragma unroll
        for (int qi = 0; qi < 2; ++qi)
#pragma unroll
          for (int rr = 0; rr < 4; ++rr)
            st[kt][qi][rr] = __builtin_amdgcn_exp2f(st[kt][qi][rr]);

      // ---- V fragments (issue early; latency hides under repack) ----
      bf16x8 vf[4][2];
#pragma unroll
      for (int dt = 0; dt < 4; ++dt) {
        vf[dt][0] = *reinterpret_cast<const bf16x8*>(Vs[cur] + (dt * 16 + l16) * 64 + ((quad ^ (l16 & 7)) << 3));
        vf[dt][1] = *reinterpret_cast<const bf16x8*>(Vs[cur] + (dt * 16 + l16) * 64 + (((4 | quad) ^ (l16 & 7)) << 3));
      }

      // ---- in-register repack: P^T -> PV A-fragments ----
      // pa[qi][g] word w(=2*w1+w0), lane quad'=2hi+lo: keys 32g+8quad'+2w+b
      // come from register pk[2g+hi][w0] of source lane (2lo+w1)*16+l16
      // (derivation: 16kt+4qs+2h+b = 32g+8quad'+4w1+2w0+b)  [verified R4]
      bf16x8 pa[2][2];
#pragma unroll
      for (int qi = 0; qi < 2; ++qi) {
        int pk[4][2];
#pragma unroll
        for (int kt = 0; kt < 4; ++kt)
#pragma unroll
          for (int h = 0; h < 2; ++h)
            asm("v_cvt_pk_bf16_f32 %0, %1, %2"
                : "=v"(pk[kt][h])
                : "v"(st[kt][qi][2 * h]), "v"(st[kt][qi][2 * h + 1]));
#pragma unroll
        for (int g = 0; g < 2; ++g) {
          int wv[4];
#pragma unroll
          for (int w1 = 0; w1 < 2; ++w1)
#pragma unroll
            for (int w0 = 0; w0 < 2; ++w0) {
              int a_ = w1 ? adr1 : adr0;
              int r0_ = __builtin_amdgcn_ds_bpermute(a_, pk[2 * g + 0][w0]);
              int r1_ = __builtin_amdgcn_ds_bpermute(a_, pk[2 * g + 1][w0]);
              wv[w1 * 2 + w0] = hi ? r1_ : r0_;
            }
          union { int i[4]; bf16x8 v; } u_;
          u_.i[0] = wv[0]; u_.i[1] = wv[1]; u_.i[2] = wv[2]; u_.i[3] = wv[3];
          pa[qi][g] = u_.v;
        }
      }

      // ---- O += P V ; l += P * ones ----
      __builtin_amdgcn_s_setprio(1);
#pragma unroll
      for (int qi = 0; qi < 2; ++qi) {
#pragma unroll
        for (int dt = 0; dt < 4; ++dt) {
          o[qi][dt] = __builtin_amdgcn_mfma_f32_16x16x32_bf16(pa[qi][0], vf[dt][0], o[qi][dt], 0, 0, 0);
          o[qi][dt] = __builtin_amdgcn_mfma_f32_16x16x32_bf16(pa[qi][1], vf[dt][1], o[qi][dt], 0, 0, 0);
        }
        lacc[qi] = __builtin_amdgcn_mfma_f32_16x16x32_bf16(pa[qi][0], ones, lacc[qi], 0, 0, 0);
        lacc[qi] = __builtin_amdgcn_mfma_f32_16x16x32_bf16(pa[qi][1], ones, lacc[qi], 0, 0, 0);
      }
      __builtin_amdgcn_s_setprio(0);
    }

    // wait next-tile loads, then release both buffers for the next iteration
    asm volatile("s_waitcnt vmcnt(0)" ::: "memory");
    __builtin_amdgcn_s_barrier();
    cur ^= 1;
  }

  // epilogue: stream raw O/L partials (fp32) to this work item's slab.
  // Slab index is the decoded work-item id w (combine maps by w).
  float* Op = Opart + (size_t)w * 8192 + wave * 32 * 64;
#pragma unroll
  for (int qi = 0; qi < 2; ++qi)
#pragma unroll
    for (int dt = 0; dt < 4; ++dt)
#pragma unroll
      for (int rr = 0; rr < 4; ++rr)
        Op[(qi * 16 + quad * 4 + rr) * 64 + dt * 16 + l16] = o[qi][dt][rr];
  if (l16 == 0) {
#pragma unroll
    for (int qi = 0; qi < 2; ++qi)
#pragma unroll
      for (int rr = 0; rr < 4; ++rr)
        Lpart[w * 128 + wave * 32 + qi * 16 + quad * 4 + rr] = lacc[qi][rr];
  }
}

// Sum partial chunks for each (bh,qb), normalize, write Yb [B,T,C] bf16.
__global__ __launch_bounds__(256)
void attn_combine(const float* __restrict__ Opart, const float* __restrict__ Lpart,
                  unsigned short* __restrict__ Yb) {
  int blk = blockIdx.x;            // 0..383 = (bh, qb)
  int bh = blk >> 4, qb = blk & 15;
  int off = (qb < 4) ? qb : (qb < 8) ? 4 + 2 * (qb - 4)
          : (qb < 12) ? 12 + 3 * (qb - 8) : 24 + 4 * (qb - 12);
  int nc = (qb >> 2) + 1;
  // attn_part used r-reversed ordering: chunk r in [off, off+nc) maps to
  // work item bh*40 + (39 - r)
  int b = bh / 12, h = bh - b * 12;
  int q0 = qb * 128;
#pragma unroll
  for (int i = 0; i < 8; ++i) {
    int idx = i * 256 + threadIdx.x;     // 0..2047 over 128 rows x 16 float4
    int row = idx >> 4, c4 = idx & 15;
    float4 s = {0.f, 0.f, 0.f, 0.f};
    float L = 0.f;
    for (int ci = 0; ci < nc; ++ci) {
      size_t pb = (size_t)(bh * 40 + 39 - (off + ci));
      float4 v = *reinterpret_cast<const float4*>(Opart + pb * 8192 + row * 64 + c4 * 4);
      s.x += v.x; s.y += v.y; s.z += v.z; s.w += v.w;
      L += Lpart[pb * 128 + row];
    }
    float rl = 1.0f / L;
    ushort4 y;
    y.x = f2b(s.x * rl); y.y = f2b(s.y * rl);
    y.z = f2b(s.z * rl); y.w = f2b(s.w * rl);
    *reinterpret_cast<ushort4*>(Yb + ((size_t)(b * 2048 + q0 + row)) * 768 + h * 64 + c4 * 4) = y;
  }
}

extern "C" void kernel_launch(void* const* d_in, const int* in_sizes, int n_in,
                              void* d_out, int out_size, void* d_ws, size_t ws_size,
                              hipStream_t stream) {
  const float* x  = (const float*)d_in[0];   // [2,2048,768]
  const float* Wa = (const float*)d_in[1];   // [2304,768]
  const float* Wp = (const float*)d_in[2];   // [768,768]
  float* out = (float*)d_out;                // [2,2048,768] fp32

  unsigned short* ws = (unsigned short*)d_ws;
  unsigned short* xb  = ws;                  // 4096*768
  unsigned short* Wab = xb  + 3145728;       // 2304*768
  unsigned short* Wpb = Wab + 1769472;       // 768*768
  unsigned short* Qb  = Wpb + 589824;        // 24*2048*64 (pre-scaled)
  unsigned short* Kb  = Qb  + 3145728;
  unsigned short* Vt  = Kb  + 3145728;       // [24][64][2048]
  unsigned short* Yb  = Vt  + 3145728;       // 4096*768
  float*          Opart = (float*)(Yb + 3145728);  // 960*128*64 fp32
  float*          Lpart = Opart + 7864320;         // 960*128 fp32

  cvt_all<<<(XN4 + WAN4 + WPN4) / 256, 256, 0, stream>>>(x, Wa, Wp, xb, Wab, Wpb);

  gemm_nt<<<dim3(4096 / BM, 2304 / BN), 256, 0, stream>>>(
      xb, Wab, 4096, 2304, 768, 0, Qb, Kb, Vt, nullptr);

  attn_part<<<960, 256, 0, stream>>>(Qb, Kb, Vt, Opart, Lpart);
  attn_combine<<<384, 256, 0, stream>>>(Opart, Lpart, Yb);

  gemm_nt<<<dim3(4096 / BM, 768 / BN), 256, 0, stream>>>(
      Yb, Wpb, 4096, 768, 768, 1, nullptr, nullptr, nullptr, out);
}